// Round 17
// baseline (290.294 us; speedup 1.0000x reference)
//
#include <hip/hip_runtime.h>
#include <stdint.h>

#define NBINS 256
#define NCOPY 32      // one sub-histogram per LDS bank; 32 KiB LDS
#define GRID 2048
#define TPB 256
// ws word layout:
#define BEST 1              // Otsu best bin index (written by k_hist last block)
#define THRS 2              // Otsu threshold bits
#define TICK 3              // ticket counter for last-block detection
#define HOFF 4              // hist bins [4..260)
#define MOFF 512            // per-block mins [512..512+GRID)
#define XOFF (512 + GRID)   // per-block maxs
#define PKOFF 8192          // packed uchar4-bins array start (word index)

typedef float f32x4 __attribute__((ext_vector_type(4)));  // nt-store compatible

// Exact replication of jnp.histogram edge: edges[i] = f32(f32(i*delta) + min)
__device__ __forceinline__ float edge_at(int i, float minv, float delta) {
    return __fadd_rn(__fmul_rn((float)i, delta), minv);
}
__device__ __forceinline__ float min4(float4 v) {
    return fminf(fminf(v.x, v.y), fminf(v.z, v.w));
}
__device__ __forceinline__ float max4(float4 v) {
    return fmaxf(fmaxf(v.x, v.y), fmaxf(v.z, v.w));
}

__global__ void __launch_bounds__(TPB) k_minmax(const float* __restrict__ in,
                                                int n, uint32_t* ws) {
    float* fws = (float*)ws;
    int n4 = n >> 2;
    int chunk = (n4 + GRID - 1) / GRID;
    int start = blockIdx.x * chunk;
    int end = start + chunk; if (end > n4) end = n4;
    const float4* in4 = (const float4*)in;
    float vmin = INFINITY, vmax = -INFINITY;

    int i = start + threadIdx.x;
    for (; i + 7 * TPB < end; i += 8 * TPB) {  // MLP=8, sequential lines
        float4 v0 = in4[i];
        float4 v1 = in4[i + TPB];
        float4 v2 = in4[i + 2 * TPB];
        float4 v3 = in4[i + 3 * TPB];
        float4 v4 = in4[i + 4 * TPB];
        float4 v5 = in4[i + 5 * TPB];
        float4 v6 = in4[i + 6 * TPB];
        float4 v7 = in4[i + 7 * TPB];
        float mn0 = fminf(fminf(min4(v0), min4(v1)), fminf(min4(v2), min4(v3)));
        float mn1 = fminf(fminf(min4(v4), min4(v5)), fminf(min4(v6), min4(v7)));
        float mx0 = fmaxf(fmaxf(max4(v0), max4(v1)), fmaxf(max4(v2), max4(v3)));
        float mx1 = fmaxf(fmaxf(max4(v4), max4(v5)), fmaxf(max4(v6), max4(v7)));
        vmin = fminf(vmin, fminf(mn0, mn1));
        vmax = fmaxf(vmax, fmaxf(mx0, mx1));
    }
    for (; i < end; i += TPB) {
        float4 v = in4[i];
        vmin = fminf(vmin, min4(v));
        vmax = fmaxf(vmax, max4(v));
    }
    for (int j = (n4 << 2) + blockIdx.x * TPB + threadIdx.x; j < n; j += GRID * TPB) {
        float v = in[j];
        vmin = fminf(vmin, v);
        vmax = fmaxf(vmax, v);
    }
#pragma unroll
    for (int off = 32; off > 0; off >>= 1) {
        vmin = fminf(vmin, __shfl_down(vmin, off));
        vmax = fmaxf(vmax, __shfl_down(vmax, off));
    }
    __shared__ float smin[4], smax[4];
    int wave = threadIdx.x >> 6, lane = threadIdx.x & 63;
    if (lane == 0) { smin[wave] = vmin; smax[wave] = vmax; }
    __syncthreads();
    if (threadIdx.x == 0) {
        fws[MOFF + blockIdx.x] = fminf(fminf(smin[0], smin[1]), fminf(smin[2], smin[3]));
        fws[XOFF + blockIdx.x] = fmaxf(fmaxf(smax[0], smax[1]), fmaxf(smax[2], smax[3]));
    }
    if (blockIdx.x == 0) {
        ws[HOFF + threadIdx.x] = 0;  // zero bins for k_hist
        if (threadIdx.x == 0) { ws[BEST] = 0; ws[THRS] = 0; ws[TICK] = 0; }
    }
}

// bin = clamp((v-min)*256/(max-min), 0, 255). ±1ulp edge misbinning shifts a
// handful of counts -> var12 argmax unaffected; final output stays EXACT (see
// k_bin_packed: verdicts correct for all ±1 misbinning cases since thresh is
// mid-bin and the center-bit uses the identical _rn formula).
__device__ __forceinline__ int bin_of(float v, float minv, float invd) {
    float t = (v - minv) * invd;
    t = fminf(fmaxf(t, 0.0f), 255.0f);
    return (int)t;
}

// bin index + (v > center_of_bin) bit, center with the SAME _rn formula Otsu uses.
__device__ __forceinline__ uint32_t binbit(float v, float minv, float invd,
                                           float delta, uint32_t* bit) {
    int j = bin_of(v, minv, invd);
    float e0 = edge_at(j, minv, delta);
    float e1 = edge_at(j + 1, minv, delta);
    float ctr = __fmul_rn(0.5f, __fadd_rn(e0, e1));
    *bit = (v > ctr) ? 1u : 0u;
    return (uint32_t)j;
}

// Histogram + pack; LAST-finishing block (ticket) computes Otsu -> ws[BEST/THRS].
// Otsu scratch + amLast flag aliased inside h[] -> LDS stays exactly 32 KiB.
__global__ void __launch_bounds__(TPB) k_hist(const float* __restrict__ in,
                                              int n, uint32_t* ws, int packed) {
    __shared__ uint32_t h[NBINS * NCOPY];  // 32 KiB
    float* hf = (float*)h;
    float* fws = (float*)ws;

    // prologue: reduce per-block min/max slots
    float lmin = INFINITY, lmax = -INFINITY;
    for (int k = threadIdx.x; k < GRID; k += TPB) {
        lmin = fminf(lmin, fws[MOFF + k]);
        lmax = fmaxf(lmax, fws[XOFF + k]);
    }
#pragma unroll
    for (int off = 32; off > 0; off >>= 1) {
        lmin = fminf(lmin, __shfl_down(lmin, off));
        lmax = fmaxf(lmax, __shfl_down(lmax, off));
    }
    int wave = threadIdx.x >> 6, lane = threadIdx.x & 63;
    if (lane == 0) { hf[wave] = lmin; hf[8 + wave] = lmax; }
    __syncthreads();
    float minv = fminf(fminf(hf[0], hf[1]), fminf(hf[2], hf[3]));
    float maxv = fmaxf(fmaxf(hf[8], hf[9]), fmaxf(hf[10], hf[11]));
    float invd = __fdiv_rn(256.0f, __fsub_rn(maxv, minv));
    float delta = __fdiv_rn(__fsub_rn(maxv, minv), 256.0f);
    __syncthreads();
    for (int i = threadIdx.x; i < NBINS * NCOPY; i += TPB) h[i] = 0;
    __syncthreads();

    int c = threadIdx.x & (NCOPY - 1);
    int n4 = n >> 2;
    int chunk = (n4 + GRID - 1) / GRID;
    int start = blockIdx.x * chunk;
    int end = start + chunk; if (end > n4) end = n4;
    const float4* in4 = (const float4*)in;
    uint32_t* bins = ws + PKOFF;
    uint8_t* bits8 = (uint8_t*)(ws + PKOFF + n4);

    for (int i = start + threadIdx.x; i < end; i += TPB) {
        float4 q = in4[i];
        uint32_t b0, b1, b2, b3;
        uint32_t j0 = binbit(q.x, minv, invd, delta, &b0);
        uint32_t j1 = binbit(q.y, minv, invd, delta, &b1);
        uint32_t j2 = binbit(q.z, minv, invd, delta, &b2);
        uint32_t j3 = binbit(q.w, minv, invd, delta, &b3);
        atomicAdd(&h[j0 * NCOPY + c], 1u);
        atomicAdd(&h[j1 * NCOPY + c], 1u);
        atomicAdd(&h[j2 * NCOPY + c], 1u);
        atomicAdd(&h[j3 * NCOPY + c], 1u);
        if (packed) {
            bins[i] = j0 | (j1 << 8) | (j2 << 16) | (j3 << 24);
            bits8[i] = (uint8_t)(b0 | (b1 << 1) | (b2 << 2) | (b3 << 3));
        }
    }
    for (int j = (n4 << 2) + blockIdx.x * TPB + threadIdx.x; j < n; j += GRID * TPB) {
        atomicAdd(&h[bin_of(in[j], minv, invd) * NCOPY + c], 1u);
    }
    __syncthreads();
    for (int b = threadIdx.x; b < NBINS; b += TPB) {
        uint32_t s = 0;
#pragma unroll
        for (int k = 0; k < NCOPY; ++k) s += h[b * NCOPY + k];
        if (s) atomicAdd(&ws[HOFF + b], s);
    }

    // ---- last-finishing block computes Otsu (once, not 2048x in k_bin) ----
    __syncthreads();           // everyone done reading h
    __threadfence();           // release our global bin adds
    if (threadIdx.x == 0) {
        uint32_t tk = atomicAdd(&ws[TICK], 1u);
        h[0] = (tk == (uint32_t)(gridDim.x - 1)) ? 1u : 0u;  // amLast flag in h
    }
    __syncthreads();
    if (h[0] == 0) return;
    __threadfence();           // acquire: see all blocks' bin adds

    {
        float* sf = (float*)h;  // alias: 7 float arrays of 256 (7 KiB < 32 KiB)
        float* cnt = sf;
        float* ctr = sf + NBINS;
        float* w1 = sf + 2 * NBINS;
        float* w2 = sf + 3 * NBINS;
        float* cs = sf + 4 * NBINS;
        float* csr = sf + 5 * NBINS;
        float* scan = sf + 6 * NBINS;
        int i = threadIdx.x;

        __syncthreads();
        cnt[i] = (float)__hip_atomic_load(&ws[HOFF + i], __ATOMIC_RELAXED,
                                          __HIP_MEMORY_SCOPE_AGENT);
        float e0 = edge_at(i, minv, delta);
        float e1 = edge_at(i + 1, minv, delta);
        ctr[i] = __fmul_rn(0.5f, __fadd_rn(e0, e1));
        __syncthreads();

        // inclusive prefix scan of cnt -> w1
        scan[i] = cnt[i]; __syncthreads();
        for (int off = 1; off < NBINS; off <<= 1) {
            float v = scan[i];
            if (i >= off) v = __fadd_rn(scan[i - off], v);
            __syncthreads(); scan[i] = v; __syncthreads();
        }
        w1[i] = scan[i]; __syncthreads();

        // inclusive prefix scan of cnt*ctr -> cs
        scan[i] = __fmul_rn(cnt[i], ctr[i]); __syncthreads();
        for (int off = 1; off < NBINS; off <<= 1) {
            float v = scan[i];
            if (i >= off) v = __fadd_rn(scan[i - off], v);
            __syncthreads(); scan[i] = v; __syncthreads();
        }
        cs[i] = scan[i]; __syncthreads();

        // inclusive suffix scan of cnt -> w2
        scan[i] = cnt[i]; __syncthreads();
        for (int off = 1; off < NBINS; off <<= 1) {
            float v = scan[i];
            if (i + off < NBINS) v = __fadd_rn(v, scan[i + off]);
            __syncthreads(); scan[i] = v; __syncthreads();
        }
        w2[i] = scan[i]; __syncthreads();

        // inclusive suffix scan of cnt*ctr -> csr
        scan[i] = __fmul_rn(cnt[i], ctr[i]); __syncthreads();
        for (int off = 1; off < NBINS; off <<= 1) {
            float v = scan[i];
            if (i + off < NBINS) v = __fadd_rn(v, scan[i + off]);
            __syncthreads(); scan[i] = v; __syncthreads();
        }
        csr[i] = scan[i]; __syncthreads();

        // var12[i] = (w1[i]*w2[i+1]) * (m1[i]-m2[i+1])^2, i in [0, 254]
        if (i < NBINS - 1) {
            float m1 = __fdiv_rn(cs[i], fmaxf(w1[i], 1.0f));
            float m2 = __fdiv_rn(csr[i + 1], fmaxf(w2[i + 1], 1.0f));
            float d = __fsub_rn(m1, m2);
            scan[i] = __fmul_rn(__fmul_rn(w1[i], w2[i + 1]), __fmul_rn(d, d));
        }
        __syncthreads();
        if (i == 0) {
            int best = 0; float bv = scan[0];
            for (int k = 1; k < NBINS - 1; ++k) {
                float v = scan[k];
                if (v > bv) { bv = v; best = k; }  // first-max like jnp.argmax
            }
            __hip_atomic_store(&ws[BEST], (uint32_t)best,
                               __ATOMIC_RELEASE, __HIP_MEMORY_SCOPE_AGENT);
            __hip_atomic_store(&ws[THRS], __float_as_uint(ctr[best]),
                               __ATOMIC_RELEASE, __HIP_MEMORY_SCOPE_AGENT);
        }
    }
}

__device__ __forceinline__ f32x4 verdict4(uint32_t u, uint32_t bt, uint32_t ubest) {
    f32x4 r;
    uint32_t j0 = u & 255u, j1 = (u >> 8) & 255u,
             j2 = (u >> 16) & 255u, j3 = (u >> 24) & 255u;
    r.x = (j0 > ubest || (j0 == ubest && (bt & 1u))) ? 1.0f : 0.0f;
    r.y = (j1 > ubest || (j1 == ubest && (bt & 2u))) ? 1.0f : 0.0f;
    r.z = (j2 > ubest || (j2 == ubest && (bt & 4u))) ? 1.0f : 0.0f;
    r.w = (j3 > ubest || (j3 == ubest && (bt & 8u))) ? 1.0f : 0.0f;
    return r;
}

// Packed path: no LDS, no prologue — two scalar loads then immediate stream.
// NT output stores keep the packed arrays L3-resident while we read them.
__global__ void __launch_bounds__(TPB) k_bin_packed(const float* __restrict__ in,
                                                    float* __restrict__ out,
                                                    int n,
                                                    const uint32_t* __restrict__ ws) {
    uint32_t ubest = ws[BEST];
    float t = __uint_as_float(ws[THRS]);

    int n4 = n >> 2;
    int chunk = (n4 + GRID - 1) / GRID;
    int start = blockIdx.x * chunk;
    int end = start + chunk; if (end > n4) end = n4;
    const uint32_t* bins = ws + PKOFF;
    const uint8_t* bits8 = (const uint8_t*)(ws + PKOFF + n4);
    f32x4* out4 = (f32x4*)out;

    for (int i = start + threadIdx.x; i < end; i += TPB) {
        f32x4 r = verdict4(bins[i], bits8[i], ubest);
        __builtin_nontemporal_store(r, &out4[i]);
    }
    for (int j = (n4 << 2) + blockIdx.x * TPB + threadIdx.x; j < n; j += GRID * TPB) {
        float r = in[j] > t ? 1.0f : 0.0f;
        __builtin_nontemporal_store(r, &out[j]);
    }
}

// Fallback (ws too small): direct re-read of f32 input.
__global__ void __launch_bounds__(TPB) k_bin_direct(const float* __restrict__ in,
                                                    float* __restrict__ out,
                                                    int n,
                                                    const uint32_t* __restrict__ ws) {
    float t = __uint_as_float(ws[THRS]);

    int n4 = n >> 2;
    int chunk = (n4 + GRID - 1) / GRID;
    int start = blockIdx.x * chunk;
    int end = start + chunk; if (end > n4) end = n4;
    const float4* in4 = (const float4*)in;
    float4* out4 = (float4*)out;
    int i = start + threadIdx.x;
    for (; i + 3 * TPB < end; i += 4 * TPB) {
        float4 v0 = in4[i];
        float4 v1 = in4[i + TPB];
        float4 v2 = in4[i + 2 * TPB];
        float4 v3 = in4[i + 3 * TPB];
        float4 r0, r1, r2, r3;
        r0.x = v0.x > t ? 1.0f : 0.0f; r0.y = v0.y > t ? 1.0f : 0.0f;
        r0.z = v0.z > t ? 1.0f : 0.0f; r0.w = v0.w > t ? 1.0f : 0.0f;
        r1.x = v1.x > t ? 1.0f : 0.0f; r1.y = v1.y > t ? 1.0f : 0.0f;
        r1.z = v1.z > t ? 1.0f : 0.0f; r1.w = v1.w > t ? 1.0f : 0.0f;
        r2.x = v2.x > t ? 1.0f : 0.0f; r2.y = v2.y > t ? 1.0f : 0.0f;
        r2.z = v2.z > t ? 1.0f : 0.0f; r2.w = v2.w > t ? 1.0f : 0.0f;
        r3.x = v3.x > t ? 1.0f : 0.0f; r3.y = v3.y > t ? 1.0f : 0.0f;
        r3.z = v3.z > t ? 1.0f : 0.0f; r3.w = v3.w > t ? 1.0f : 0.0f;
        out4[i] = r0;
        out4[i + TPB] = r1;
        out4[i + 2 * TPB] = r2;
        out4[i + 3 * TPB] = r3;
    }
    for (; i < end; i += TPB) {
        float4 v = in4[i];
        float4 r;
        r.x = v.x > t ? 1.0f : 0.0f;
        r.y = v.y > t ? 1.0f : 0.0f;
        r.z = v.z > t ? 1.0f : 0.0f;
        r.w = v.w > t ? 1.0f : 0.0f;
        out4[i] = r;
    }
    for (int j = (n4 << 2) + blockIdx.x * TPB + threadIdx.x; j < n; j += GRID * TPB) {
        out[j] = in[j] > t ? 1.0f : 0.0f;
    }
}

extern "C" void kernel_launch(void* const* d_in, const int* in_sizes, int n_in,
                              void* d_out, int out_size, void* d_ws, size_t ws_size,
                              hipStream_t stream) {
    const float* in = (const float*)d_in[0];
    float* out = (float*)d_out;
    uint32_t* ws = (uint32_t*)d_ws;
    int n = in_sizes[0];
    int n4 = n >> 2;

    size_t need = (size_t)(PKOFF + (size_t)n4) * 4 + (size_t)n4;  // bins + bits
    int packed = (ws_size >= need) ? 1 : 0;

    hipLaunchKernelGGL(k_minmax, dim3(GRID), dim3(TPB), 0, stream, in, n, ws);
    hipLaunchKernelGGL(k_hist, dim3(GRID), dim3(TPB), 0, stream, in, n, ws, packed);
    if (packed) {
        hipLaunchKernelGGL(k_bin_packed, dim3(GRID), dim3(TPB), 0, stream,
                           in, out, n, ws);
    } else {
        hipLaunchKernelGGL(k_bin_direct, dim3(GRID), dim3(TPB), 0, stream,
                           in, out, n, ws);
    }
}

// Round 18
// 142.095 us; speedup vs baseline: 2.0430x; 2.0430x over previous
//
#include <hip/hip_runtime.h>
#include <stdint.h>

#define NBINS 256
#define NCOPY 32      // one sub-histogram per LDS bank; 32 KiB LDS
#define GRID 2048
#define TPB 256
// ws word layout:
#define HOFF 4              // hist bins [4..260)
#define MOFF 512            // per-block mins [512..512+GRID)
#define XOFF (512 + GRID)   // per-block maxs
#define PKOFF 8192          // packed uchar4-bins array start (word index)

typedef float f32x4 __attribute__((ext_vector_type(4)));  // nt-store compatible

// Exact replication of jnp.histogram edge: edges[i] = f32(f32(i*delta) + min)
__device__ __forceinline__ float edge_at(int i, float minv, float delta) {
    return __fadd_rn(__fmul_rn((float)i, delta), minv);
}
__device__ __forceinline__ float min4(float4 v) {
    return fminf(fminf(v.x, v.y), fminf(v.z, v.w));
}
__device__ __forceinline__ float max4(float4 v) {
    return fmaxf(fmaxf(v.x, v.y), fmaxf(v.z, v.w));
}

__global__ void __launch_bounds__(TPB) k_minmax(const float* __restrict__ in,
                                                int n, uint32_t* ws) {
    float* fws = (float*)ws;
    int n4 = n >> 2;
    int chunk = (n4 + GRID - 1) / GRID;
    int start = blockIdx.x * chunk;
    int end = start + chunk; if (end > n4) end = n4;
    const float4* in4 = (const float4*)in;
    float vmin = INFINITY, vmax = -INFINITY;

    int i = start + threadIdx.x;
    for (; i + 7 * TPB < end; i += 8 * TPB) {  // MLP=8, sequential lines
        float4 v0 = in4[i];
        float4 v1 = in4[i + TPB];
        float4 v2 = in4[i + 2 * TPB];
        float4 v3 = in4[i + 3 * TPB];
        float4 v4 = in4[i + 4 * TPB];
        float4 v5 = in4[i + 5 * TPB];
        float4 v6 = in4[i + 6 * TPB];
        float4 v7 = in4[i + 7 * TPB];
        float mn0 = fminf(fminf(min4(v0), min4(v1)), fminf(min4(v2), min4(v3)));
        float mn1 = fminf(fminf(min4(v4), min4(v5)), fminf(min4(v6), min4(v7)));
        float mx0 = fmaxf(fmaxf(max4(v0), max4(v1)), fmaxf(max4(v2), max4(v3)));
        float mx1 = fmaxf(fmaxf(max4(v4), max4(v5)), fmaxf(max4(v6), max4(v7)));
        vmin = fminf(vmin, fminf(mn0, mn1));
        vmax = fmaxf(vmax, fmaxf(mx0, mx1));
    }
    for (; i < end; i += TPB) {
        float4 v = in4[i];
        vmin = fminf(vmin, min4(v));
        vmax = fmaxf(vmax, max4(v));
    }
    for (int j = (n4 << 2) + blockIdx.x * TPB + threadIdx.x; j < n; j += GRID * TPB) {
        float v = in[j];
        vmin = fminf(vmin, v);
        vmax = fmaxf(vmax, v);
    }
#pragma unroll
    for (int off = 32; off > 0; off >>= 1) {
        vmin = fminf(vmin, __shfl_down(vmin, off));
        vmax = fmaxf(vmax, __shfl_down(vmax, off));
    }
    __shared__ float smin[4], smax[4];
    int wave = threadIdx.x >> 6, lane = threadIdx.x & 63;
    if (lane == 0) { smin[wave] = vmin; smax[wave] = vmax; }
    __syncthreads();
    if (threadIdx.x == 0) {
        fws[MOFF + blockIdx.x] = fminf(fminf(smin[0], smin[1]), fminf(smin[2], smin[3]));
        fws[XOFF + blockIdx.x] = fmaxf(fmaxf(smax[0], smax[1]), fmaxf(smax[2], smax[3]));
    }
    if (blockIdx.x == 0) ws[HOFF + threadIdx.x] = 0;  // zero bins for k_hist
}

// bin = clamp((v-min)*256/(max-min), 0, 255). ±1ulp edge misbinning shifts a
// handful of counts -> var12 argmax unaffected; final output stays EXACT (see
// k_bin_packed: per-element verdicts correct for all misbinning cases since
// thresh is mid-bin and the center-bit uses the identical _rn formula).
__device__ __forceinline__ int bin_of(float v, float minv, float invd) {
    float t = (v - minv) * invd;
    t = fminf(fmaxf(t, 0.0f), 255.0f);
    return (int)t;
}

// bin index + (v > center_of_bin) bit, center with the SAME _rn formula Otsu uses.
__device__ __forceinline__ uint32_t binbit(float v, float minv, float invd,
                                           float delta, uint32_t* bit) {
    int j = bin_of(v, minv, invd);
    float e0 = edge_at(j, minv, delta);
    float e1 = edge_at(j + 1, minv, delta);
    float ctr = __fmul_rn(0.5f, __fadd_rn(e0, e1));
    *bit = (v > ctr) ? 1u : 0u;
    return (uint32_t)j;
}

// Histogram; when packed!=0 also emits per-quad uchar4 bins + 4 "v>center" bits.
// MLP=1 main loop: R15 showed batched loads + interleaved pack stores regress.
// NO device-scope fences anywhere in this kernel (R17 lesson: one __threadfence
// per block forces L2 writebacks of the packed arrays -> 2x kernel slowdown).
__global__ void __launch_bounds__(TPB) k_hist(const float* __restrict__ in,
                                              int n, uint32_t* ws, int packed) {
    __shared__ uint32_t h[NBINS * NCOPY];  // 32 KiB
    float* hf = (float*)h;
    float* fws = (float*)ws;

    // prologue: reduce per-block min/max slots
    float lmin = INFINITY, lmax = -INFINITY;
    for (int k = threadIdx.x; k < GRID; k += TPB) {
        lmin = fminf(lmin, fws[MOFF + k]);
        lmax = fmaxf(lmax, fws[XOFF + k]);
    }
#pragma unroll
    for (int off = 32; off > 0; off >>= 1) {
        lmin = fminf(lmin, __shfl_down(lmin, off));
        lmax = fmaxf(lmax, __shfl_down(lmax, off));
    }
    int wave = threadIdx.x >> 6, lane = threadIdx.x & 63;
    if (lane == 0) { hf[wave] = lmin; hf[8 + wave] = lmax; }
    __syncthreads();
    float minv = fminf(fminf(hf[0], hf[1]), fminf(hf[2], hf[3]));
    float maxv = fmaxf(fmaxf(hf[8], hf[9]), fmaxf(hf[10], hf[11]));
    float invd = __fdiv_rn(256.0f, __fsub_rn(maxv, minv));
    float delta = __fdiv_rn(__fsub_rn(maxv, minv), 256.0f);
    __syncthreads();
    for (int i = threadIdx.x; i < NBINS * NCOPY; i += TPB) h[i] = 0;
    __syncthreads();

    int c = threadIdx.x & (NCOPY - 1);
    int n4 = n >> 2;
    int chunk = (n4 + GRID - 1) / GRID;
    int start = blockIdx.x * chunk;
    int end = start + chunk; if (end > n4) end = n4;
    const float4* in4 = (const float4*)in;
    uint32_t* bins = ws + PKOFF;
    uint8_t* bits8 = (uint8_t*)(ws + PKOFF + n4);

    for (int i = start + threadIdx.x; i < end; i += TPB) {
        float4 q = in4[i];
        uint32_t b0, b1, b2, b3;
        uint32_t j0 = binbit(q.x, minv, invd, delta, &b0);
        uint32_t j1 = binbit(q.y, minv, invd, delta, &b1);
        uint32_t j2 = binbit(q.z, minv, invd, delta, &b2);
        uint32_t j3 = binbit(q.w, minv, invd, delta, &b3);
        atomicAdd(&h[j0 * NCOPY + c], 1u);
        atomicAdd(&h[j1 * NCOPY + c], 1u);
        atomicAdd(&h[j2 * NCOPY + c], 1u);
        atomicAdd(&h[j3 * NCOPY + c], 1u);
        if (packed) {
            bins[i] = j0 | (j1 << 8) | (j2 << 16) | (j3 << 24);
            bits8[i] = (uint8_t)(b0 | (b1 << 1) | (b2 << 2) | (b3 << 3));
        }
    }
    for (int j = (n4 << 2) + blockIdx.x * TPB + threadIdx.x; j < n; j += GRID * TPB) {
        atomicAdd(&h[bin_of(in[j], minv, invd) * NCOPY + c], 1u);
    }
    __syncthreads();
    for (int b = threadIdx.x; b < NBINS; b += TPB) {
        uint32_t s = 0;
#pragma unroll
        for (int k = 0; k < NCOPY; ++k) s += h[b * NCOPY + k];
        if (s) atomicAdd(&ws[HOFF + b], s);
    }
}

// Shared Otsu prologue: returns best bin (and thresh for the scalar tail).
// Runs redundantly in every k_bin block — cheaper than any cross-block fence.
__device__ __forceinline__ void otsu_prologue(const uint32_t* __restrict__ ws,
                                              int* best_out, float* thresh_out) {
    __shared__ float cnt[NBINS], ctr[NBINS], w1[NBINS], w2[NBINS],
                     cs[NBINS], csr[NBINS], scan[NBINS];
    __shared__ int sbest;
    const float* fws = (const float*)ws;
    int i = threadIdx.x;

    float lmin = INFINITY, lmax = -INFINITY;
    for (int k = i; k < GRID; k += TPB) {
        lmin = fminf(lmin, fws[MOFF + k]);
        lmax = fmaxf(lmax, fws[XOFF + k]);
    }
#pragma unroll
    for (int off = 32; off > 0; off >>= 1) {
        lmin = fminf(lmin, __shfl_down(lmin, off));
        lmax = fmaxf(lmax, __shfl_down(lmax, off));
    }
    int wave = i >> 6, lane = i & 63;
    if (lane == 0) { scan[wave] = lmin; scan[8 + wave] = lmax; }
    __syncthreads();
    float minv = fminf(fminf(scan[0], scan[1]), fminf(scan[2], scan[3]));
    float maxv = fmaxf(fmaxf(scan[8], scan[9]), fmaxf(scan[10], scan[11]));
    float delta = __fdiv_rn(__fsub_rn(maxv, minv), 256.0f);
    __syncthreads();

    cnt[i] = (float)ws[HOFF + i];
    float e0 = edge_at(i, minv, delta);
    float e1 = edge_at(i + 1, minv, delta);
    ctr[i] = __fmul_rn(0.5f, __fadd_rn(e0, e1));
    __syncthreads();

    scan[i] = cnt[i]; __syncthreads();
    for (int off = 1; off < NBINS; off <<= 1) {
        float v = scan[i];
        if (i >= off) v = __fadd_rn(scan[i - off], v);
        __syncthreads(); scan[i] = v; __syncthreads();
    }
    w1[i] = scan[i]; __syncthreads();

    scan[i] = __fmul_rn(cnt[i], ctr[i]); __syncthreads();
    for (int off = 1; off < NBINS; off <<= 1) {
        float v = scan[i];
        if (i >= off) v = __fadd_rn(scan[i - off], v);
        __syncthreads(); scan[i] = v; __syncthreads();
    }
    cs[i] = scan[i]; __syncthreads();

    scan[i] = cnt[i]; __syncthreads();
    for (int off = 1; off < NBINS; off <<= 1) {
        float v = scan[i];
        if (i + off < NBINS) v = __fadd_rn(v, scan[i + off]);
        __syncthreads(); scan[i] = v; __syncthreads();
    }
    w2[i] = scan[i]; __syncthreads();

    scan[i] = __fmul_rn(cnt[i], ctr[i]); __syncthreads();
    for (int off = 1; off < NBINS; off <<= 1) {
        float v = scan[i];
        if (i + off < NBINS) v = __fadd_rn(v, scan[i + off]);
        __syncthreads(); scan[i] = v; __syncthreads();
    }
    csr[i] = scan[i]; __syncthreads();

    if (i < NBINS - 1) {
        float m1 = __fdiv_rn(cs[i], fmaxf(w1[i], 1.0f));
        float m2 = __fdiv_rn(csr[i + 1], fmaxf(w2[i + 1], 1.0f));
        float d = __fsub_rn(m1, m2);
        scan[i] = __fmul_rn(__fmul_rn(w1[i], w2[i + 1]), __fmul_rn(d, d));
    }
    __syncthreads();
    if (i == 0) {
        int best = 0; float bv = scan[0];
        for (int k = 1; k < NBINS - 1; ++k) {
            float v = scan[k];
            if (v > bv) { bv = v; best = k; }  // first-max like jnp.argmax
        }
        sbest = best;
        scan[0] = ctr[best];
    }
    __syncthreads();
    *best_out = sbest;
    *thresh_out = scan[0];
    __syncthreads();
}

__device__ __forceinline__ f32x4 verdict4(uint32_t u, uint32_t bt, uint32_t ubest) {
    f32x4 r;
    uint32_t j0 = u & 255u, j1 = (u >> 8) & 255u,
             j2 = (u >> 16) & 255u, j3 = (u >> 24) & 255u;
    r.x = (j0 > ubest || (j0 == ubest && (bt & 1u))) ? 1.0f : 0.0f;
    r.y = (j1 > ubest || (j1 == ubest && (bt & 2u))) ? 1.0f : 0.0f;
    r.z = (j2 > ubest || (j2 == ubest && (bt & 4u))) ? 1.0f : 0.0f;
    r.w = (j3 > ubest || (j3 == ubest && (bt & 8u))) ? 1.0f : 0.0f;
    return r;
}

// Packed path: read bins+bits (42MB, L3-hot) instead of 134MB f32. Output via
// NT stores so the 134MB write stream doesn't evict the packed arrays from L3
// while we're reading them (output is never re-read).
__global__ void __launch_bounds__(TPB) k_bin_packed(const float* __restrict__ in,
                                                    float* __restrict__ out,
                                                    int n,
                                                    const uint32_t* __restrict__ ws) {
    int best; float t;
    otsu_prologue(ws, &best, &t);

    int n4 = n >> 2;
    int chunk = (n4 + GRID - 1) / GRID;
    int start = blockIdx.x * chunk;
    int end = start + chunk; if (end > n4) end = n4;
    const uint32_t* bins = ws + PKOFF;
    const uint8_t* bits8 = (const uint8_t*)(ws + PKOFF + n4);
    f32x4* out4 = (f32x4*)out;
    uint32_t ubest = (uint32_t)best;

    for (int i = start + threadIdx.x; i < end; i += TPB) {
        f32x4 r = verdict4(bins[i], bits8[i], ubest);
        __builtin_nontemporal_store(r, &out4[i]);
    }
    for (int j = (n4 << 2) + blockIdx.x * TPB + threadIdx.x; j < n; j += GRID * TPB) {
        float r = in[j] > t ? 1.0f : 0.0f;
        __builtin_nontemporal_store(r, &out[j]);
    }
}

// Fallback (ws too small): direct re-read of f32 input (R13 path).
__global__ void __launch_bounds__(TPB) k_bin_direct(const float* __restrict__ in,
                                                    float* __restrict__ out,
                                                    int n,
                                                    const uint32_t* __restrict__ ws) {
    int best; float t;
    otsu_prologue(ws, &best, &t);

    int n4 = n >> 2;
    int chunk = (n4 + GRID - 1) / GRID;
    int start = blockIdx.x * chunk;
    int end = start + chunk; if (end > n4) end = n4;
    const float4* in4 = (const float4*)in;
    float4* out4 = (float4*)out;
    int i = start + threadIdx.x;
    for (; i + 3 * TPB < end; i += 4 * TPB) {
        float4 v0 = in4[i];
        float4 v1 = in4[i + TPB];
        float4 v2 = in4[i + 2 * TPB];
        float4 v3 = in4[i + 3 * TPB];
        float4 r0, r1, r2, r3;
        r0.x = v0.x > t ? 1.0f : 0.0f; r0.y = v0.y > t ? 1.0f : 0.0f;
        r0.z = v0.z > t ? 1.0f : 0.0f; r0.w = v0.w > t ? 1.0f : 0.0f;
        r1.x = v1.x > t ? 1.0f : 0.0f; r1.y = v1.y > t ? 1.0f : 0.0f;
        r1.z = v1.z > t ? 1.0f : 0.0f; r1.w = v1.w > t ? 1.0f : 0.0f;
        r2.x = v2.x > t ? 1.0f : 0.0f; r2.y = v2.y > t ? 1.0f : 0.0f;
        r2.z = v2.z > t ? 1.0f : 0.0f; r2.w = v2.w > t ? 1.0f : 0.0f;
        r3.x = v3.x > t ? 1.0f : 0.0f; r3.y = v3.y > t ? 1.0f : 0.0f;
        r3.z = v3.z > t ? 1.0f : 0.0f; r3.w = v3.w > t ? 1.0f : 0.0f;
        out4[i] = r0;
        out4[i + TPB] = r1;
        out4[i + 2 * TPB] = r2;
        out4[i + 3 * TPB] = r3;
    }
    for (; i < end; i += TPB) {
        float4 v = in4[i];
        float4 r;
        r.x = v.x > t ? 1.0f : 0.0f;
        r.y = v.y > t ? 1.0f : 0.0f;
        r.z = v.z > t ? 1.0f : 0.0f;
        r.w = v.w > t ? 1.0f : 0.0f;
        out4[i] = r;
    }
    for (int j = (n4 << 2) + blockIdx.x * TPB + threadIdx.x; j < n; j += GRID * TPB) {
        out[j] = in[j] > t ? 1.0f : 0.0f;
    }
}

extern "C" void kernel_launch(void* const* d_in, const int* in_sizes, int n_in,
                              void* d_out, int out_size, void* d_ws, size_t ws_size,
                              hipStream_t stream) {
    const float* in = (const float*)d_in[0];
    float* out = (float*)d_out;
    uint32_t* ws = (uint32_t*)d_ws;
    int n = in_sizes[0];
    int n4 = n >> 2;

    size_t need = (size_t)(PKOFF + (size_t)n4) * 4 + (size_t)n4;  // bins + bits
    int packed = (ws_size >= need) ? 1 : 0;

    hipLaunchKernelGGL(k_minmax, dim3(GRID), dim3(TPB), 0, stream, in, n, ws);
    hipLaunchKernelGGL(k_hist, dim3(GRID), dim3(TPB), 0, stream, in, n, ws, packed);
    if (packed) {
        hipLaunchKernelGGL(k_bin_packed, dim3(GRID), dim3(TPB), 0, stream,
                           in, out, n, ws);
    } else {
        hipLaunchKernelGGL(k_bin_direct, dim3(GRID), dim3(TPB), 0, stream,
                           in, out, n, ws);
    }
}